// Round 25
// baseline (660.349 us; speedup 1.0000x reference)
//
#include <hip/hip_runtime.h>
#include <stdint.h>

typedef short short8  __attribute__((ext_vector_type(8)));
typedef short short4v __attribute__((ext_vector_type(4)));
typedef float f32x4   __attribute__((ext_vector_type(4)));

#define B_    4
#define Q_    1024
#define H_    32
#define HKV_  8
#define D_    128
#define HID_  4096
#define NQKV_ 6144
#define SCALE_ 0.08838834764831845f

__device__ __forceinline__ short f2bf(float f) {
  unsigned u = __builtin_bit_cast(unsigned, f);
  u += 0x7fffu + ((u >> 16) & 1u);          // RNE
  return (short)(u >> 16);
}
__device__ __forceinline__ float bf2f(short s) {
  unsigned u = ((unsigned)(unsigned short)s) << 16;
  return __builtin_bit_cast(float, u);
}

__device__ __forceinline__ void gload_lds16(const void* g, void* l) {
  __builtin_amdgcn_global_load_lds(
      (__attribute__((address_space(1))) void*)(uintptr_t)(g),
      (__attribute__((address_space(3))) void*)(l), 16, 0, 0);
}

__device__ __forceinline__ f32x4 mfma16x16x32(short8 a, short8 b, f32x4 c) {
  return __builtin_amdgcn_mfma_f32_16x16x32_bf16(a, b, c, 0, 0, 0);
}

// ---------------- f32 -> bf16 flat convert ----------------
__global__ __launch_bounds__(256) void k_cvt(const float* __restrict__ src,
                                             short* __restrict__ dst, int n) {
  int i = (blockIdx.x * 256 + threadIdx.x) * 4;
  if (i + 3 < n) {
    float4 v = *reinterpret_cast<const float4*>(src + i);
    short4v o;
    o[0] = f2bf(v.x); o[1] = f2bf(v.y); o[2] = f2bf(v.z); o[3] = f2bf(v.w);
    *reinterpret_cast<short4v*>(dst + i) = o;
  }
}

// ------- f32 [R][C] -> bf16 [C][R] transpose-convert -------
__global__ __launch_bounds__(256) void k_cvt_t(const float* __restrict__ src,
                                               short* __restrict__ dst, int R, int C) {
  __shared__ float tile[32][33];
  int c0 = blockIdx.x * 32, r0 = blockIdx.y * 32;
  int tx = threadIdx.x & 31, ty = threadIdx.x >> 5;
#pragma unroll
  for (int i = 0; i < 4; ++i)
    tile[ty + i * 8][tx] = src[(size_t)(r0 + ty + i * 8) * C + c0 + tx];
  __syncthreads();
#pragma unroll
  for (int i = 0; i < 4; ++i)
    dst[(size_t)(c0 + ty + i * 8) * R + r0 + tx] = f2bf(tile[tx][ty + i * 8]);
}

// ------- V transpose: kv v-half [s][d] per (b,hkv) -> v_t[bh][d][s]  (bf16) -------
__global__ __launch_bounds__(256) void k_vt(const short* __restrict__ kv,
                                            short* __restrict__ vt) {
  __shared__ short tile[32][33];
  const int bh = blockIdx.z;          // b*8 + hkv
  const int s0 = blockIdx.x * 32, d0 = blockIdx.y * 32;
  const int tx = threadIdx.x & 31, ty = threadIdx.x >> 5;
  const int b = bh >> 3, hkv = bh & 7;
  const short* src = kv + (size_t)(b * Q_) * 2048 + 1024 + hkv * D_;
#pragma unroll
  for (int i = 0; i < 4; ++i)
    tile[ty + i * 8][tx] = src[(size_t)(s0 + ty + i * 8) * 2048 + d0 + tx];
  __syncthreads();
  short* dst = vt + (size_t)bh * 128 * 1024;
#pragma unroll
  for (int i = 0; i < 4; ++i)
    dst[(size_t)(d0 + ty + i * 8) * 1024 + s0 + tx] = tile[tx][ty + i * 8];
}

// ------- GEMM1 (m97 structure, BK=64 double-stage; block-uniform split store) -------
__global__ __launch_bounds__(256) void k_gemm1(const short* __restrict__ A,
                                               const short* __restrict__ Bt,
                                               short* __restrict__ qout,
                                               short* __restrict__ kvout) {
  __shared__ alignas(16) short Asm[2][128 * 32];
  __shared__ alignas(16) short Bsm[2][128 * 32];
  const int tid = threadIdx.x;
  const int wave = tid >> 6, lane = tid & 63;
  const int G = lane >> 4, r = lane & 15;
  const int wm = wave >> 1, wn = wave & 1;
  const size_t Arow0 = (size_t)blockIdx.y * 128;
  const size_t Brow0 = (size_t)blockIdx.x * 128;
  const int K = HID_;
  const int ldrow = lane >> 2, ldcol = (lane & 3) * 8;
  short* Cb; size_t ldc, cb;
  if (Brow0 < (size_t)HID_) { Cb = qout; ldc = HID_; cb = Brow0; }
  else                      { Cb = kvout; ldc = 2048; cb = Brow0 - HID_; }
  f32x4 acc[4][4] = {};
  for (int k0 = 0; k0 < K; k0 += 64) {
    __syncthreads();
#pragma unroll
    for (int h = 0; h < 2; ++h)
#pragma unroll
      for (int i = 0; i < 2; ++i) {
        int c = wave * 2 + i;
        gload_lds16(A + (Arow0 + c * 16 + ldrow) * K + k0 + h * 32 + ldcol, &Asm[h][c * 512]);
        gload_lds16(Bt + (Brow0 + c * 16 + ldrow) * K + k0 + h * 32 + ldcol, &Bsm[h][c * 512]);
      }
    asm volatile("s_waitcnt vmcnt(0)" ::: "memory");
    __syncthreads();
#pragma unroll
    for (int h = 0; h < 2; ++h) {
      short8 af[4], bf[4];
#pragma unroll
      for (int i = 0; i < 4; ++i)
        af[i] = *reinterpret_cast<const short8*>(&Asm[h][(wm * 64 + i * 16 + r) * 32 + G * 8]);
#pragma unroll
      for (int j = 0; j < 4; ++j)
        bf[j] = *reinterpret_cast<const short8*>(&Bsm[h][(wn * 64 + j * 16 + r) * 32 + G * 8]);
#pragma unroll
      for (int i = 0; i < 4; ++i)
#pragma unroll
        for (int j = 0; j < 4; ++j)
          acc[i][j] = mfma16x16x32(af[i], bf[j], acc[i][j]);
    }
  }
#pragma unroll
  for (int i = 0; i < 4; ++i)
#pragma unroll
    for (int j = 0; j < 4; ++j)
#pragma unroll
      for (int rr = 0; rr < 4; ++rr) {
        size_t row = Arow0 + wm * 64 + i * 16 + G * 4 + rr;
        size_t col = cb + wn * 64 + j * 16 + r;
        Cb[row * ldc + col] = f2bf(acc[i][j][rr]);
      }
}

// ------- GEMM2 (m97 structure, BK=64 double-stage, 128x128): C f32 = A * Bt^T -------
__global__ __launch_bounds__(256) void k_gemm2(const short* __restrict__ A,
                                               const short* __restrict__ Bt,
                                               float* __restrict__ C) {
  __shared__ alignas(16) short Asm[2][128 * 32];
  __shared__ alignas(16) short Bsm[2][128 * 32];
  const int tid = threadIdx.x;
  const int wave = tid >> 6, lane = tid & 63;
  const int G = lane >> 4, r = lane & 15;
  const int wm = wave >> 1, wn = wave & 1;
  const size_t Arow0 = (size_t)blockIdx.y * 128;
  const size_t Brow0 = (size_t)blockIdx.x * 128;
  const int K = HID_;
  const int ldrow = lane >> 2, ldcol = (lane & 3) * 8;
  f32x4 acc[4][4] = {};
  for (int k0 = 0; k0 < K; k0 += 64) {
    __syncthreads();
#pragma unroll
    for (int h = 0; h < 2; ++h)
#pragma unroll
      for (int i = 0; i < 2; ++i) {
        int c = wave * 2 + i;
        gload_lds16(A + (Arow0 + c * 16 + ldrow) * K + k0 + h * 32 + ldcol, &Asm[h][c * 512]);
        gload_lds16(Bt + (Brow0 + c * 16 + ldrow) * K + k0 + h * 32 + ldcol, &Bsm[h][c * 512]);
      }
    asm volatile("s_waitcnt vmcnt(0)" ::: "memory");
    __syncthreads();
#pragma unroll
    for (int h = 0; h < 2; ++h) {
      short8 af[4], bf[4];
#pragma unroll
      for (int i = 0; i < 4; ++i)
        af[i] = *reinterpret_cast<const short8*>(&Asm[h][(wm * 64 + i * 16 + r) * 32 + G * 8]);
#pragma unroll
      for (int j = 0; j < 4; ++j)
        bf[j] = *reinterpret_cast<const short8*>(&Bsm[h][(wn * 64 + j * 16 + r) * 32 + G * 8]);
#pragma unroll
      for (int i = 0; i < 4; ++i)
#pragma unroll
        for (int j = 0; j < 4; ++j)
          acc[i][j] = mfma16x16x32(af[i], bf[j], acc[i][j]);
    }
  }
#pragma unroll
  for (int i = 0; i < 4; ++i)
#pragma unroll
    for (int j = 0; j < 4; ++j)
#pragma unroll
      for (int rr = 0; rr < 4; ++rr) {
        size_t row = Arow0 + wm * 64 + i * 16 + G * 4 + rr;
        size_t col = Brow0 + wn * 64 + j * 16 + r;
        C[row * (size_t)HID_ + col] = acc[i][j][rr];
      }
}

// ------- NeoX RoPE, merged q+k dispatch; pos = t & 1023 (derived) -------
__global__ __launch_bounds__(256) void k_rope2(short* __restrict__ q,
                                               short* __restrict__ kv) {
  const int t = blockIdx.x;
  const float pos = (float)(t & (Q_ - 1));
  short* qrow = q + (size_t)t * HID_;
  short* krow = kv + (size_t)t * 2048;
  for (int i = threadIdx.x; i < (H_ + HKV_) * 64; i += 256) {
    int h = i >> 6, j = i & 63;
    short* row = (h < H_) ? (qrow + h * D_) : (krow + (h - H_) * D_);
    float fr = powf(10000.0f, -(float)j * (1.0f / 64.0f));
    float sn, cs;
    sincosf(pos * fr, &sn, &cs);
    float x1 = bf2f(row[j]);
    float x2 = bf2f(row[64 + j]);
    row[j]      = f2bf(x1 * cs - x2 * sn);
    row[64 + j] = f2bf(x1 * sn + x2 * cs);
  }
}

// ------- MFMA flash attention (causal, GQA rep=4) + T5 + T14; register P-path -------
// PV uses sigma-paired fragments: pf[u] holds P at s-offset (u>>2)*16+G*4+(u&3), and the
// V fragment is read with the SAME slot map (two b64 at +G*4 and +G*4+16) -> sums identical
// to the canonical layout (k-slot bijection cancels). Verified value-equivalent in r1<->r2.
// q bf16 [B*Q][HID]; kv bf16 [B*Q][2048] (k cols 0..1023); v_t bf16 [b*8+hkv][128][1024]
__global__ __launch_bounds__(256) void k_attn(const short* __restrict__ qbf,
                                              const short* __restrict__ kv,
                                              const short* __restrict__ vt,
                                              short* __restrict__ attn) {
  const int qt = blockIdx.x;   // 16
  const int h  = blockIdx.y;   // 32
  const int b  = blockIdx.z;   // 4
  const int hkv = h >> 2;
  const int tid = threadIdx.x, wave = tid >> 6, lane = tid & 63;
  const int G = lane >> 4, r = lane & 15;
  const int q0w = qt * 64 + wave * 16;
  const float NEG_INF = -__builtin_inff();
  __shared__ alignas(16) short Ksm[32 * 136];   // [s][d] padded
  __shared__ alignas(16) short Vsm[128 * 40];   // V^T [d][s] padded
  short8 qf[4];
  {
    const short* qrow = qbf + ((size_t)(b * Q_ + q0w + r)) * HID_ + h * D_;
#pragma unroll
    for (int ds = 0; ds < 4; ++ds)
      qf[ds] = *reinterpret_cast<const short8*>(qrow + ds * 32 + G * 8);
  }
  f32x4 acc[8] = {};
  float m_run = NEG_INF, l_run = 0.f;
  const int ntiles = qt * 2 + 2;
  const int my_q = q0w + r;
  const int my_q_hi = q0w + 15;
  const int krow = tid >> 3, kd0 = (tid & 7) * 16;
  const int vd = tid >> 2, vsc = (tid & 3) * 8;
  const short* vt_base = vt + (size_t)(b * 8 + hkv) * 128 * 1024;
  // T14 issue-early registers (one KV tile in flight)
  uint4 kreg0, kreg1, vreg0, vreg1;
  auto preload = [&](int st) {
    const short* gk = kv + ((size_t)(b * Q_ + st * 32 + krow)) * 2048 + hkv * D_ + kd0;
    kreg0 = *reinterpret_cast<const uint4*>(gk);
    kreg1 = *reinterpret_cast<const uint4*>(gk + 8);
    vreg0 = *reinterpret_cast<const uint4*>(vt_base + (size_t)vd * 1024 + st * 32 + vsc);
    vreg1 = *reinterpret_cast<const uint4*>(vt_base + (size_t)(vd + 64) * 1024 + st * 32 + vsc);
  };
  preload(0);
  for (int st = 0; st < ntiles; ++st) {
    __syncthreads();
    {
      *reinterpret_cast<uint4*>(&Ksm[krow * 136 + kd0])     = kreg0;
      *reinterpret_cast<uint4*>(&Ksm[krow * 136 + kd0 + 8]) = kreg1;
      *reinterpret_cast<uint4*>(&Vsm[vd * 40 + vsc])        = vreg0;
      *reinterpret_cast<uint4*>(&Vsm[(vd + 64) * 40 + vsc]) = vreg1;
    }
    __syncthreads();
    if (st + 1 < ntiles) preload(st + 1);   // latency hides under compute below
    if (st * 32 <= my_q_hi) {
      f32x4 sacc[2] = {};
      __builtin_amdgcn_s_setprio(1);
#pragma unroll
      for (int sb = 0; sb < 2; ++sb)
#pragma unroll
        for (int ds = 0; ds < 4; ++ds) {
          short8 kf = *reinterpret_cast<const short8*>(&Ksm[(sb * 16 + r) * 136 + ds * 32 + G * 8]);
          sacc[sb] = mfma16x16x32(kf, qf[ds], sacc[sb]);
        }
      __builtin_amdgcn_s_setprio(0);
      float vals[8];
      float mymax = NEG_INF;
#pragma unroll
      for (int sb = 0; sb < 2; ++sb)
#pragma unroll
        for (int j = 0; j < 4; ++j) {
          int sIdx = st * 32 + sb * 16 + G * 4 + j;
          float v = sacc[sb][j] * SCALE_;
          v = (sIdx <= my_q) ? v : NEG_INF;
          vals[sb * 4 + j] = v;
          mymax = fmaxf(mymax, v);
        }
      mymax = fmaxf(mymax, __shfl_xor(mymax, 16));
      mymax = fmaxf(mymax, __shfl_xor(mymax, 32));
      float m_new = fmaxf(m_run, mymax);
      float factor = __expf(m_run - m_new);
      float psum = 0.f;
      short8 pf;
#pragma unroll
      for (int i = 0; i < 8; ++i) {
        float p = __expf(vals[i] - m_new);
        psum += p;
        pf[i] = f2bf(p);              // sigma_A slot u -> s-offset (u>>2)*16 + G*4 + (u&3)
      }
      psum += __shfl_xor(psum, 16);
      psum += __shfl_xor(psum, 32);
      l_run = l_run * factor + psum;
      m_run = m_new;
      float frow[4];
#pragma unroll
      for (int rr = 0; rr < 4; ++rr) frow[rr] = __shfl(factor, G * 4 + rr);
#pragma unroll
      for (int dt = 0; dt < 8; ++dt)
#pragma unroll
        for (int rr = 0; rr < 4; ++rr) acc[dt][rr] *= frow[rr];
      __builtin_amdgcn_s_setprio(1);
#pragma unroll
      for (int dt = 0; dt < 8; ++dt) {
        // sigma_B matches sigma_A: slots 0-3 from s-offset G*4+j, slots 4-7 from 16+G*4+j
        const short* vp = &Vsm[(dt * 16 + r) * 40 + G * 4];
        short4v v0 = *reinterpret_cast<const short4v*>(vp);
        short4v v1 = *reinterpret_cast<const short4v*>(vp + 16);
        short8 vf;
#pragma unroll
        for (int j = 0; j < 4; ++j) { vf[j] = v0[j]; vf[4 + j] = v1[j]; }
        acc[dt] = mfma16x16x32(pf, vf, acc[dt]);
      }
      __builtin_amdgcn_s_setprio(0);
    }
  }
  float inv = 1.0f / l_run;
  float irow[4];
#pragma unroll
  for (int rr = 0; rr < 4; ++rr) irow[rr] = __shfl(inv, G * 4 + rr);
#pragma unroll
  for (int dt = 0; dt < 8; ++dt)
#pragma unroll
    for (int rr = 0; rr < 4; ++rr) {
      size_t rowi = (size_t)(b * Q_ + q0w + G * 4 + rr) * HID_;
      attn[rowi + h * D_ + dt * 16 + r] = f2bf(acc[dt][rr] * irow[rr]);
    }
}

// ---------------- launch ----------------
extern "C" void kernel_launch(void* const* d_in, const int* in_sizes, int n_in,
                              void* d_out, int out_size, void* d_ws, size_t ws_size,
                              hipStream_t stream) {
  const float* hidden = (const float*)d_in[0];
  const float* w_qkv  = (const float*)d_in[1];
  const float* w_o    = (const float*)d_in[2];
  float* out = (float*)d_out;
  char* ws = (char*)d_ws;
  char* od = (char*)d_out;
  // scratch layout (ws 64 MiB + d_out 64 MiB):
  //   d_out[ 0:32M) hid_bf   -> dead after GEMM1
  //   d_out[32M:64M) q_bf    -> roped; dead after attn
  //   ws   [ 0:48M) wqkvT    -> dead after GEMM1
  //   ws   [48M:64M) kv_ws   -> k-half roped; dead after attn
  //   ws   [32M:40M) v_t     -> written after GEMM1 (dead wqkvT tail); dead after attn
  //   ws   [ 0:32M) attn_bf  (after GEMM1)
  //   ws   [32M:64M) woT     (after attn; clobbers v_t + kv_ws)
  short* hid_bf  = (short*)(od + 0);
  short* q_bf    = (short*)(od + 33554432);
  short* wqkvT   = (short*)(ws + 0);
  short* kv_ws   = (short*)(ws + 50331648);
  short* v_t     = (short*)(ws + 33554432);
  short* attn_bf = (short*)(ws + 0);
  short* woT     = (short*)(ws + 33554432);

  k_cvt<<<dim3(16384), dim3(256), 0, stream>>>(hidden, hid_bf, HID_ * B_ * Q_);
  k_cvt_t<<<dim3(192, 128), dim3(256), 0, stream>>>(w_qkv, wqkvT, HID_, NQKV_);
  // GEMM1: one dispatch, N=6144 (48x32 = 1536 wgs), BK=64 double-stage
  k_gemm1<<<dim3(48, 32), dim3(256), 0, stream>>>(hid_bf, wqkvT, q_bf, kv_ws);
  // RoPE in place, merged dispatch: q (32 heads) + k (8 heads, kv cols 0..1023)
  k_rope2<<<dim3(B_ * Q_), dim3(256), 0, stream>>>(q_bf, kv_ws);
  // V transpose (v-half of kv untouched by rope) -> v_t
  k_vt<<<dim3(32, 4, 32), dim3(256), 0, stream>>>(kv_ws, v_t);
  // attention -> attn_bf (ws+0, wqkvT dead)
  k_attn<<<dim3(16, 32, 4), dim3(256), 0, stream>>>(q_bf, kv_ws, v_t, attn_bf);
  // w_o^T into ws[32M:64M) (v_t + kv dead after attn), then GEMM2 -> d_out f32
  k_cvt_t<<<dim3(128, 128), dim3(256), 0, stream>>>(w_o, woT, HID_, HID_);
  // GEMM2: 128x128 tiles
  k_gemm2<<<dim3(32, 32), dim3(256), 0, stream>>>(attn_bf, woT, out);
}

// Round 26
// 649.445 us; speedup vs baseline: 1.0168x; 1.0168x over previous
//
#include <hip/hip_runtime.h>
#include <stdint.h>

typedef short short8  __attribute__((ext_vector_type(8)));
typedef short short4v __attribute__((ext_vector_type(4)));
typedef float f32x4   __attribute__((ext_vector_type(4)));

#define B_    4
#define Q_    1024
#define H_    32
#define HKV_  8
#define D_    128
#define HID_  4096
#define NQKV_ 6144
#define SCALE_ 0.08838834764831845f

__device__ __forceinline__ short f2bf(float f) {
  unsigned u = __builtin_bit_cast(unsigned, f);
  u += 0x7fffu + ((u >> 16) & 1u);          // RNE
  return (short)(u >> 16);
}
__device__ __forceinline__ float bf2f(short s) {
  unsigned u = ((unsigned)(unsigned short)s) << 16;
  return __builtin_bit_cast(float, u);
}

__device__ __forceinline__ void gload_lds16(const void* g, void* l) {
  __builtin_amdgcn_global_load_lds(
      (__attribute__((address_space(1))) void*)(uintptr_t)(g),
      (__attribute__((address_space(3))) void*)(l), 16, 0, 0);
}

__device__ __forceinline__ f32x4 mfma16x16x32(short8 a, short8 b, f32x4 c) {
  return __builtin_amdgcn_mfma_f32_16x16x32_bf16(a, b, c, 0, 0, 0);
}

// ---------------- f32 -> bf16 flat convert ----------------
__global__ __launch_bounds__(256) void k_cvt(const float* __restrict__ src,
                                             short* __restrict__ dst, int n) {
  int i = (blockIdx.x * 256 + threadIdx.x) * 4;
  if (i + 3 < n) {
    float4 v = *reinterpret_cast<const float4*>(src + i);
    short4v o;
    o[0] = f2bf(v.x); o[1] = f2bf(v.y); o[2] = f2bf(v.z); o[3] = f2bf(v.w);
    *reinterpret_cast<short4v*>(dst + i) = o;
  }
}

// ------- f32 [R][C] -> bf16 [C][R] transpose-convert -------
__global__ __launch_bounds__(256) void k_cvt_t(const float* __restrict__ src,
                                               short* __restrict__ dst, int R, int C) {
  __shared__ float tile[32][33];
  int c0 = blockIdx.x * 32, r0 = blockIdx.y * 32;
  int tx = threadIdx.x & 31, ty = threadIdx.x >> 5;
#pragma unroll
  for (int i = 0; i < 4; ++i)
    tile[ty + i * 8][tx] = src[(size_t)(r0 + ty + i * 8) * C + c0 + tx];
  __syncthreads();
#pragma unroll
  for (int i = 0; i < 4; ++i)
    dst[(size_t)(c0 + ty + i * 8) * R + r0 + tx] = f2bf(tile[tx][ty + i * 8]);
}

// ------- V transpose: kv v-half [s][d] per (b,hkv) -> v_t[bh][d][s]  (bf16) -------
__global__ __launch_bounds__(256) void k_vt(const short* __restrict__ kv,
                                            short* __restrict__ vt) {
  __shared__ short tile[32][33];
  const int bh = blockIdx.z;          // b*8 + hkv
  const int s0 = blockIdx.x * 32, d0 = blockIdx.y * 32;
  const int tx = threadIdx.x & 31, ty = threadIdx.x >> 5;
  const int b = bh >> 3, hkv = bh & 7;
  const short* src = kv + (size_t)(b * Q_) * 2048 + 1024 + hkv * D_;
#pragma unroll
  for (int i = 0; i < 4; ++i)
    tile[ty + i * 8][tx] = src[(size_t)(s0 + ty + i * 8) * 2048 + d0 + tx];
  __syncthreads();
  short* dst = vt + (size_t)bh * 128 * 1024;
#pragma unroll
  for (int i = 0; i < 4; ++i)
    dst[(size_t)(d0 + ty + i * 8) * 1024 + s0 + tx] = tile[tx][ty + i * 8];
}

// ------- GEMM1 (m97 structure, BK=64 double-stage; block-uniform split store) -------
__global__ __launch_bounds__(256) void k_gemm1(const short* __restrict__ A,
                                               const short* __restrict__ Bt,
                                               short* __restrict__ qout,
                                               short* __restrict__ kvout) {
  __shared__ alignas(16) short Asm[2][128 * 32];
  __shared__ alignas(16) short Bsm[2][128 * 32];
  const int tid = threadIdx.x;
  const int wave = tid >> 6, lane = tid & 63;
  const int G = lane >> 4, r = lane & 15;
  const int wm = wave >> 1, wn = wave & 1;
  const size_t Arow0 = (size_t)blockIdx.y * 128;
  const size_t Brow0 = (size_t)blockIdx.x * 128;
  const int K = HID_;
  const int ldrow = lane >> 2, ldcol = (lane & 3) * 8;
  short* Cb; size_t ldc, cb;
  if (Brow0 < (size_t)HID_) { Cb = qout; ldc = HID_; cb = Brow0; }
  else                      { Cb = kvout; ldc = 2048; cb = Brow0 - HID_; }
  f32x4 acc[4][4] = {};
  for (int k0 = 0; k0 < K; k0 += 64) {
    __syncthreads();
#pragma unroll
    for (int h = 0; h < 2; ++h)
#pragma unroll
      for (int i = 0; i < 2; ++i) {
        int c = wave * 2 + i;
        gload_lds16(A + (Arow0 + c * 16 + ldrow) * K + k0 + h * 32 + ldcol, &Asm[h][c * 512]);
        gload_lds16(Bt + (Brow0 + c * 16 + ldrow) * K + k0 + h * 32 + ldcol, &Bsm[h][c * 512]);
      }
    asm volatile("s_waitcnt vmcnt(0)" ::: "memory");
    __syncthreads();
#pragma unroll
    for (int h = 0; h < 2; ++h) {
      short8 af[4], bf[4];
#pragma unroll
      for (int i = 0; i < 4; ++i)
        af[i] = *reinterpret_cast<const short8*>(&Asm[h][(wm * 64 + i * 16 + r) * 32 + G * 8]);
#pragma unroll
      for (int j = 0; j < 4; ++j)
        bf[j] = *reinterpret_cast<const short8*>(&Bsm[h][(wn * 64 + j * 16 + r) * 32 + G * 8]);
#pragma unroll
      for (int i = 0; i < 4; ++i)
#pragma unroll
        for (int j = 0; j < 4; ++j)
          acc[i][j] = mfma16x16x32(af[i], bf[j], acc[i][j]);
    }
  }
#pragma unroll
  for (int i = 0; i < 4; ++i)
#pragma unroll
    for (int j = 0; j < 4; ++j)
#pragma unroll
      for (int rr = 0; rr < 4; ++rr) {
        size_t row = Arow0 + wm * 64 + i * 16 + G * 4 + rr;
        size_t col = cb + wn * 64 + j * 16 + r;
        Cb[row * ldc + col] = f2bf(acc[i][j][rr]);
      }
}

// ------- GEMM2 (m97 structure, BK=64 double-stage, 128x128): C f32 = A * Bt^T -------
__global__ __launch_bounds__(256) void k_gemm2(const short* __restrict__ A,
                                               const short* __restrict__ Bt,
                                               float* __restrict__ C) {
  __shared__ alignas(16) short Asm[2][128 * 32];
  __shared__ alignas(16) short Bsm[2][128 * 32];
  const int tid = threadIdx.x;
  const int wave = tid >> 6, lane = tid & 63;
  const int G = lane >> 4, r = lane & 15;
  const int wm = wave >> 1, wn = wave & 1;
  const size_t Arow0 = (size_t)blockIdx.y * 128;
  const size_t Brow0 = (size_t)blockIdx.x * 128;
  const int K = HID_;
  const int ldrow = lane >> 2, ldcol = (lane & 3) * 8;
  f32x4 acc[4][4] = {};
  for (int k0 = 0; k0 < K; k0 += 64) {
    __syncthreads();
#pragma unroll
    for (int h = 0; h < 2; ++h)
#pragma unroll
      for (int i = 0; i < 2; ++i) {
        int c = wave * 2 + i;
        gload_lds16(A + (Arow0 + c * 16 + ldrow) * K + k0 + h * 32 + ldcol, &Asm[h][c * 512]);
        gload_lds16(Bt + (Brow0 + c * 16 + ldrow) * K + k0 + h * 32 + ldcol, &Bsm[h][c * 512]);
      }
    asm volatile("s_waitcnt vmcnt(0)" ::: "memory");
    __syncthreads();
#pragma unroll
    for (int h = 0; h < 2; ++h) {
      short8 af[4], bf[4];
#pragma unroll
      for (int i = 0; i < 4; ++i)
        af[i] = *reinterpret_cast<const short8*>(&Asm[h][(wm * 64 + i * 16 + r) * 32 + G * 8]);
#pragma unroll
      for (int j = 0; j < 4; ++j)
        bf[j] = *reinterpret_cast<const short8*>(&Bsm[h][(wn * 64 + j * 16 + r) * 32 + G * 8]);
#pragma unroll
      for (int i = 0; i < 4; ++i)
#pragma unroll
        for (int j = 0; j < 4; ++j)
          acc[i][j] = mfma16x16x32(af[i], bf[j], acc[i][j]);
    }
  }
#pragma unroll
  for (int i = 0; i < 4; ++i)
#pragma unroll
    for (int j = 0; j < 4; ++j)
#pragma unroll
      for (int rr = 0; rr < 4; ++rr) {
        size_t row = Arow0 + wm * 64 + i * 16 + G * 4 + rr;
        size_t col = Brow0 + wn * 64 + j * 16 + r;
        C[row * (size_t)HID_ + col] = acc[i][j][rr];
      }
}

// ------- NeoX RoPE, merged q+k dispatch; pos = t & 1023 (derived) -------
__global__ __launch_bounds__(256) void k_rope2(short* __restrict__ q,
                                               short* __restrict__ kv) {
  const int t = blockIdx.x;
  const float pos = (float)(t & (Q_ - 1));
  short* qrow = q + (size_t)t * HID_;
  short* krow = kv + (size_t)t * 2048;
  for (int i = threadIdx.x; i < (H_ + HKV_) * 64; i += 256) {
    int h = i >> 6, j = i & 63;
    short* row = (h < H_) ? (qrow + h * D_) : (krow + (h - H_) * D_);
    float fr = powf(10000.0f, -(float)j * (1.0f / 64.0f));
    float sn, cs;
    sincosf(pos * fr, &sn, &cs);
    float x1 = bf2f(row[j]);
    float x2 = bf2f(row[64 + j]);
    row[j]      = f2bf(x1 * cs - x2 * sn);
    row[64 + j] = f2bf(x1 * sn + x2 * cs);
  }
}

// ------- MFMA flash attention (causal, GQA rep=4) + T5 setprio + T14 async-stage -------
// q bf16 [B*Q][HID]; kv bf16 [B*Q][2048] (k cols 0..1023); v_t bf16 [b*8+hkv][128][1024]
__global__ __launch_bounds__(256) void k_attn(const short* __restrict__ qbf,
                                              const short* __restrict__ kv,
                                              const short* __restrict__ vt,
                                              short* __restrict__ attn) {
  const int qt = blockIdx.x;   // 16
  const int h  = blockIdx.y;   // 32
  const int b  = blockIdx.z;   // 4
  const int hkv = h >> 2;
  const int tid = threadIdx.x, wave = tid >> 6, lane = tid & 63;
  const int G = lane >> 4, r = lane & 15;
  const int q0w = qt * 64 + wave * 16;
  const float NEG_INF = -__builtin_inff();
  __shared__ alignas(16) short Ksm[32 * 136];   // [s][d] padded
  __shared__ alignas(16) short Vsm[128 * 40];   // V^T [d][s] padded
  __shared__ alignas(16) short Psm[4][16][40];  // per-wave P [q][s]
  short8 qf[4];
  {
    const short* qrow = qbf + ((size_t)(b * Q_ + q0w + r)) * HID_ + h * D_;
#pragma unroll
    for (int ds = 0; ds < 4; ++ds)
      qf[ds] = *reinterpret_cast<const short8*>(qrow + ds * 32 + G * 8);
  }
  f32x4 acc[8] = {};
  float m_run = NEG_INF, l_run = 0.f;
  const int ntiles = qt * 2 + 2;
  const int my_q = q0w + r;
  const int my_q_hi = q0w + 15;
  const int krow = tid >> 3, kd0 = (tid & 7) * 16;
  const int vd = tid >> 2, vsc = (tid & 3) * 8;
  const short* vt_base = vt + (size_t)(b * 8 + hkv) * 128 * 1024;
  // T14 issue-early registers (one KV tile in flight)
  uint4 kreg0, kreg1, vreg0, vreg1;
  auto preload = [&](int st) {
    const short* gk = kv + ((size_t)(b * Q_ + st * 32 + krow)) * 2048 + hkv * D_ + kd0;
    kreg0 = *reinterpret_cast<const uint4*>(gk);
    kreg1 = *reinterpret_cast<const uint4*>(gk + 8);
    vreg0 = *reinterpret_cast<const uint4*>(vt_base + (size_t)vd * 1024 + st * 32 + vsc);
    vreg1 = *reinterpret_cast<const uint4*>(vt_base + (size_t)(vd + 64) * 1024 + st * 32 + vsc);
  };
  preload(0);
  for (int st = 0; st < ntiles; ++st) {
    __syncthreads();
    {
      *reinterpret_cast<uint4*>(&Ksm[krow * 136 + kd0])     = kreg0;
      *reinterpret_cast<uint4*>(&Ksm[krow * 136 + kd0 + 8]) = kreg1;
      *reinterpret_cast<uint4*>(&Vsm[vd * 40 + vsc])        = vreg0;
      *reinterpret_cast<uint4*>(&Vsm[(vd + 64) * 40 + vsc]) = vreg1;
    }
    __syncthreads();
    if (st + 1 < ntiles) preload(st + 1);   // latency hides under compute below
    if (st * 32 <= my_q_hi) {
      f32x4 sacc[2] = {};
      __builtin_amdgcn_s_setprio(1);
#pragma unroll
      for (int sb = 0; sb < 2; ++sb)
#pragma unroll
        for (int ds = 0; ds < 4; ++ds) {
          short8 kf = *reinterpret_cast<const short8*>(&Ksm[(sb * 16 + r) * 136 + ds * 32 + G * 8]);
          sacc[sb] = mfma16x16x32(kf, qf[ds], sacc[sb]);
        }
      __builtin_amdgcn_s_setprio(0);
      float vals[8];
      float mymax = NEG_INF;
#pragma unroll
      for (int sb = 0; sb < 2; ++sb)
#pragma unroll
        for (int j = 0; j < 4; ++j) {
          int sIdx = st * 32 + sb * 16 + G * 4 + j;
          float v = sacc[sb][j] * SCALE_;
          v = (sIdx <= my_q) ? v : NEG_INF;
          vals[sb * 4 + j] = v;
          mymax = fmaxf(mymax, v);
        }
      mymax = fmaxf(mymax, __shfl_xor(mymax, 16));
      mymax = fmaxf(mymax, __shfl_xor(mymax, 32));
      float m_new = fmaxf(m_run, mymax);
      float factor = __expf(m_run - m_new);
      float psum = 0.f;
      float pv_[8];
#pragma unroll
      for (int i = 0; i < 8; ++i) {
        float p = __expf(vals[i] - m_new);
        psum += p;
        pv_[i] = p;
      }
      psum += __shfl_xor(psum, 16);
      psum += __shfl_xor(psum, 32);
      l_run = l_run * factor + psum;
      m_run = m_new;
#pragma unroll
      for (int i = 0; i < 8; ++i)
        Psm[wave][r][(i >> 2) * 16 + G * 4 + (i & 3)] = f2bf(pv_[i]);
      asm volatile("s_waitcnt lgkmcnt(0)" ::: "memory");
      __builtin_amdgcn_sched_barrier(0);
      short8 pf = *reinterpret_cast<const short8*>(&Psm[wave][r][G * 8]);
      float frow[4];
#pragma unroll
      for (int rr = 0; rr < 4; ++rr) frow[rr] = __shfl(factor, G * 4 + rr);
#pragma unroll
      for (int dt = 0; dt < 8; ++dt)
#pragma unroll
        for (int rr = 0; rr < 4; ++rr) acc[dt][rr] *= frow[rr];
      __builtin_amdgcn_s_setprio(1);
#pragma unroll
      for (int dt = 0; dt < 8; ++dt) {
        short8 vf = *reinterpret_cast<const short8*>(&Vsm[(dt * 16 + r) * 40 + G * 8]);
        acc[dt] = mfma16x16x32(pf, vf, acc[dt]);
      }
      __builtin_amdgcn_s_setprio(0);
    }
  }
  float inv = 1.0f / l_run;
  float irow[4];
#pragma unroll
  for (int rr = 0; rr < 4; ++rr) irow[rr] = __shfl(inv, G * 4 + rr);
#pragma unroll
  for (int dt = 0; dt < 8; ++dt)
#pragma unroll
    for (int rr = 0; rr < 4; ++rr) {
      size_t rowi = (size_t)(b * Q_ + q0w + G * 4 + rr) * HID_;
      attn[rowi + h * D_ + dt * 16 + r] = f2bf(acc[dt][rr] * irow[rr]);
    }
}

// ---------------- launch ----------------
extern "C" void kernel_launch(void* const* d_in, const int* in_sizes, int n_in,
                              void* d_out, int out_size, void* d_ws, size_t ws_size,
                              hipStream_t stream) {
  const float* hidden = (const float*)d_in[0];
  const float* w_qkv  = (const float*)d_in[1];
  const float* w_o    = (const float*)d_in[2];
  float* out = (float*)d_out;
  char* ws = (char*)d_ws;
  char* od = (char*)d_out;
  // scratch layout (ws 64 MiB + d_out 64 MiB):
  //   d_out[ 0:32M) hid_bf   -> dead after GEMM1
  //   d_out[32M:64M) q_bf    -> roped; dead after attn
  //   ws   [ 0:48M) wqkvT    -> dead after GEMM1
  //   ws   [48M:64M) kv_ws   -> k-half roped; dead after attn
  //   ws   [32M:40M) v_t     -> written after GEMM1 (dead wqkvT tail); dead after attn
  //   ws   [ 0:32M) attn_bf  (after GEMM1)
  //   ws   [32M:64M) woT     (after attn; clobbers v_t + kv_ws)
  short* hid_bf  = (short*)(od + 0);
  short* q_bf    = (short*)(od + 33554432);
  short* wqkvT   = (short*)(ws + 0);
  short* kv_ws   = (short*)(ws + 50331648);
  short* v_t     = (short*)(ws + 33554432);
  short* attn_bf = (short*)(ws + 0);
  short* woT     = (short*)(ws + 33554432);

  k_cvt<<<dim3(16384), dim3(256), 0, stream>>>(hidden, hid_bf, HID_ * B_ * Q_);
  k_cvt_t<<<dim3(192, 128), dim3(256), 0, stream>>>(w_qkv, wqkvT, HID_, NQKV_);
  // GEMM1: one dispatch, N=6144 (48x32 = 1536 wgs), BK=64 double-stage
  k_gemm1<<<dim3(48, 32), dim3(256), 0, stream>>>(hid_bf, wqkvT, q_bf, kv_ws);
  // RoPE in place, merged dispatch: q (32 heads) + k (8 heads, kv cols 0..1023)
  k_rope2<<<dim3(B_ * Q_), dim3(256), 0, stream>>>(q_bf, kv_ws);
  // V transpose (v-half of kv untouched by rope) -> v_t
  k_vt<<<dim3(32, 4, 32), dim3(256), 0, stream>>>(kv_ws, v_t);
  // attention -> attn_bf (ws+0, wqkvT dead)
  k_attn<<<dim3(16, 32, 4), dim3(256), 0, stream>>>(q_bf, kv_ws, v_t, attn_bf);
  // w_o^T into ws[32M:64M) (v_t + kv dead after attn), then GEMM2 -> d_out f32
  k_cvt_t<<<dim3(128, 128), dim3(256), 0, stream>>>(w_o, woT, HID_, HID_);
  // GEMM2: 128x128 tiles
  k_gemm2<<<dim3(32, 32), dim3(256), 0, stream>>>(attn_bf, woT, out);
}

// Round 27
// 649.397 us; speedup vs baseline: 1.0169x; 1.0001x over previous
//
#include <hip/hip_runtime.h>
#include <stdint.h>

typedef short short8  __attribute__((ext_vector_type(8)));
typedef short short4v __attribute__((ext_vector_type(4)));
typedef float f32x4   __attribute__((ext_vector_type(4)));

#define B_    4
#define Q_    1024
#define H_    32
#define HKV_  8
#define D_    128
#define HID_  4096
#define NQKV_ 6144
#define SCALE_ 0.08838834764831845f

__device__ __forceinline__ short f2bf(float f) {
  unsigned u = __builtin_bit_cast(unsigned, f);
  u += 0x7fffu + ((u >> 16) & 1u);          // RNE
  return (short)(u >> 16);
}
__device__ __forceinline__ float bf2f(short s) {
  unsigned u = ((unsigned)(unsigned short)s) << 16;
  return __builtin_bit_cast(float, u);
}

__device__ __forceinline__ void gload_lds16(const void* g, void* l) {
  __builtin_amdgcn_global_load_lds(
      (__attribute__((address_space(1))) void*)(uintptr_t)(g),
      (__attribute__((address_space(3))) void*)(l), 16, 0, 0);
}

__device__ __forceinline__ f32x4 mfma16x16x32(short8 a, short8 b, f32x4 c) {
  return __builtin_amdgcn_mfma_f32_16x16x32_bf16(a, b, c, 0, 0, 0);
}

// ---------------- f32 -> bf16 flat convert ----------------
__global__ __launch_bounds__(256) void k_cvt(const float* __restrict__ src,
                                             short* __restrict__ dst, int n) {
  int i = (blockIdx.x * 256 + threadIdx.x) * 4;
  if (i + 3 < n) {
    float4 v = *reinterpret_cast<const float4*>(src + i);
    short4v o;
    o[0] = f2bf(v.x); o[1] = f2bf(v.y); o[2] = f2bf(v.z); o[3] = f2bf(v.w);
    *reinterpret_cast<short4v*>(dst + i) = o;
  }
}

// ------- f32 [R][C] -> bf16 [C][R] transpose-convert -------
__global__ __launch_bounds__(256) void k_cvt_t(const float* __restrict__ src,
                                               short* __restrict__ dst, int R, int C) {
  __shared__ float tile[32][33];
  int c0 = blockIdx.x * 32, r0 = blockIdx.y * 32;
  int tx = threadIdx.x & 31, ty = threadIdx.x >> 5;
#pragma unroll
  for (int i = 0; i < 4; ++i)
    tile[ty + i * 8][tx] = src[(size_t)(r0 + ty + i * 8) * C + c0 + tx];
  __syncthreads();
#pragma unroll
  for (int i = 0; i < 4; ++i)
    dst[(size_t)(c0 + ty + i * 8) * R + r0 + tx] = f2bf(tile[tx][ty + i * 8]);
}

// ------- GEMM1 (m97 structure, BK=64 double-stage; block-uniform split store) -------
__global__ __launch_bounds__(256) void k_gemm1(const short* __restrict__ A,
                                               const short* __restrict__ Bt,
                                               short* __restrict__ qout,
                                               short* __restrict__ kvout) {
  __shared__ alignas(16) short Asm[2][128 * 32];
  __shared__ alignas(16) short Bsm[2][128 * 32];
  const int tid = threadIdx.x;
  const int wave = tid >> 6, lane = tid & 63;
  const int G = lane >> 4, r = lane & 15;
  const int wm = wave >> 1, wn = wave & 1;
  const size_t Arow0 = (size_t)blockIdx.y * 128;
  const size_t Brow0 = (size_t)blockIdx.x * 128;
  const int K = HID_;
  const int ldrow = lane >> 2, ldcol = (lane & 3) * 8;
  short* Cb; size_t ldc, cb;
  if (Brow0 < (size_t)HID_) { Cb = qout; ldc = HID_; cb = Brow0; }
  else                      { Cb = kvout; ldc = 2048; cb = Brow0 - HID_; }
  f32x4 acc[4][4] = {};
  for (int k0 = 0; k0 < K; k0 += 64) {
    __syncthreads();
#pragma unroll
    for (int h = 0; h < 2; ++h)
#pragma unroll
      for (int i = 0; i < 2; ++i) {
        int c = wave * 2 + i;
        gload_lds16(A + (Arow0 + c * 16 + ldrow) * K + k0 + h * 32 + ldcol, &Asm[h][c * 512]);
        gload_lds16(Bt + (Brow0 + c * 16 + ldrow) * K + k0 + h * 32 + ldcol, &Bsm[h][c * 512]);
      }
    asm volatile("s_waitcnt vmcnt(0)" ::: "memory");
    __syncthreads();
#pragma unroll
    for (int h = 0; h < 2; ++h) {
      short8 af[4], bf[4];
#pragma unroll
      for (int i = 0; i < 4; ++i)
        af[i] = *reinterpret_cast<const short8*>(&Asm[h][(wm * 64 + i * 16 + r) * 32 + G * 8]);
#pragma unroll
      for (int j = 0; j < 4; ++j)
        bf[j] = *reinterpret_cast<const short8*>(&Bsm[h][(wn * 64 + j * 16 + r) * 32 + G * 8]);
#pragma unroll
      for (int i = 0; i < 4; ++i)
#pragma unroll
        for (int j = 0; j < 4; ++j)
          acc[i][j] = mfma16x16x32(af[i], bf[j], acc[i][j]);
    }
  }
#pragma unroll
  for (int i = 0; i < 4; ++i)
#pragma unroll
    for (int j = 0; j < 4; ++j)
#pragma unroll
      for (int rr = 0; rr < 4; ++rr) {
        size_t row = Arow0 + wm * 64 + i * 16 + G * 4 + rr;
        size_t col = cb + wn * 64 + j * 16 + r;
        Cb[row * ldc + col] = f2bf(acc[i][j][rr]);
      }
}

// ------- GEMM2 (m97 structure, BK=64 double-stage, 128x128): C f32 = A * Bt^T -------
__global__ __launch_bounds__(256) void k_gemm2(const short* __restrict__ A,
                                               const short* __restrict__ Bt,
                                               float* __restrict__ C) {
  __shared__ alignas(16) short Asm[2][128 * 32];
  __shared__ alignas(16) short Bsm[2][128 * 32];
  const int tid = threadIdx.x;
  const int wave = tid >> 6, lane = tid & 63;
  const int G = lane >> 4, r = lane & 15;
  const int wm = wave >> 1, wn = wave & 1;
  const size_t Arow0 = (size_t)blockIdx.y * 128;
  const size_t Brow0 = (size_t)blockIdx.x * 128;
  const int K = HID_;
  const int ldrow = lane >> 2, ldcol = (lane & 3) * 8;
  f32x4 acc[4][4] = {};
  for (int k0 = 0; k0 < K; k0 += 64) {
    __syncthreads();
#pragma unroll
    for (int h = 0; h < 2; ++h)
#pragma unroll
      for (int i = 0; i < 2; ++i) {
        int c = wave * 2 + i;
        gload_lds16(A + (Arow0 + c * 16 + ldrow) * K + k0 + h * 32 + ldcol, &Asm[h][c * 512]);
        gload_lds16(Bt + (Brow0 + c * 16 + ldrow) * K + k0 + h * 32 + ldcol, &Bsm[h][c * 512]);
      }
    asm volatile("s_waitcnt vmcnt(0)" ::: "memory");
    __syncthreads();
#pragma unroll
    for (int h = 0; h < 2; ++h) {
      short8 af[4], bf[4];
#pragma unroll
      for (int i = 0; i < 4; ++i)
        af[i] = *reinterpret_cast<const short8*>(&Asm[h][(wm * 64 + i * 16 + r) * 32 + G * 8]);
#pragma unroll
      for (int j = 0; j < 4; ++j)
        bf[j] = *reinterpret_cast<const short8*>(&Bsm[h][(wn * 64 + j * 16 + r) * 32 + G * 8]);
#pragma unroll
      for (int i = 0; i < 4; ++i)
#pragma unroll
        for (int j = 0; j < 4; ++j)
          acc[i][j] = mfma16x16x32(af[i], bf[j], acc[i][j]);
    }
  }
#pragma unroll
  for (int i = 0; i < 4; ++i)
#pragma unroll
    for (int j = 0; j < 4; ++j)
#pragma unroll
      for (int rr = 0; rr < 4; ++rr) {
        size_t row = Arow0 + wm * 64 + i * 16 + G * 4 + rr;
        size_t col = Brow0 + wn * 64 + j * 16 + r;
        C[row * (size_t)HID_ + col] = acc[i][j][rr];
      }
}

// ------- fused prep: blocks [0,4096) NeoX RoPE (q+k); blocks [4096,8192) V transpose ----
// Halves are data-independent (rope: q + kv k-half; vt: kv v-half -> v_t). Per-block code
// byte-identical to the proven k_rope2 / k_vt kernels; branch is block-uniform.
__global__ __launch_bounds__(256) void k_prep(short* __restrict__ q,
                                              short* __restrict__ kv,
                                              short* __restrict__ vt) {
  __shared__ short tile[32][33];
  const int bid = blockIdx.x;
  if (bid < B_ * Q_) {
    const int t = bid;
    const float pos = (float)(t & (Q_ - 1));
    short* qrow = q + (size_t)t * HID_;
    short* krow = kv + (size_t)t * 2048;
    for (int i = threadIdx.x; i < (H_ + HKV_) * 64; i += 256) {
      int h = i >> 6, j = i & 63;
      short* row = (h < H_) ? (qrow + h * D_) : (krow + (h - H_) * D_);
      float fr = powf(10000.0f, -(float)j * (1.0f / 64.0f));
      float sn, cs;
      sincosf(pos * fr, &sn, &cs);
      float x1 = bf2f(row[j]);
      float x2 = bf2f(row[64 + j]);
      row[j]      = f2bf(x1 * cs - x2 * sn);
      row[64 + j] = f2bf(x1 * sn + x2 * cs);
    }
  } else {
    const int idx = bid - B_ * Q_;
    const int bh = idx >> 7;                 // 32: b*8 + hkv
    const int d0 = ((idx >> 5) & 3) * 32;    // 4 d-tiles
    const int s0 = (idx & 31) * 32;          // 32 s-tiles
    const int tx = threadIdx.x & 31, ty = threadIdx.x >> 5;
    const int b = bh >> 3, hkv = bh & 7;
    const short* src = kv + (size_t)(b * Q_) * 2048 + 1024 + hkv * D_;
#pragma unroll
    for (int i = 0; i < 4; ++i)
      tile[ty + i * 8][tx] = src[(size_t)(s0 + ty + i * 8) * 2048 + d0 + tx];
    __syncthreads();
    short* dst = vt + (size_t)bh * 128 * 1024;
#pragma unroll
    for (int i = 0; i < 4; ++i)
      dst[(size_t)(d0 + ty + i * 8) * 1024 + s0 + tx] = tile[tx][ty + i * 8];
  }
}

// ------- MFMA flash attention (causal, GQA rep=4) + T5 setprio + T14 async-stage -------
// q bf16 [B*Q][HID]; kv bf16 [B*Q][2048] (k cols 0..1023); v_t bf16 [b*8+hkv][128][1024]
__global__ __launch_bounds__(256) void k_attn(const short* __restrict__ qbf,
                                              const short* __restrict__ kv,
                                              const short* __restrict__ vt,
                                              short* __restrict__ attn) {
  const int qt = blockIdx.x;   // 16
  const int h  = blockIdx.y;   // 32
  const int b  = blockIdx.z;   // 4
  const int hkv = h >> 2;
  const int tid = threadIdx.x, wave = tid >> 6, lane = tid & 63;
  const int G = lane >> 4, r = lane & 15;
  const int q0w = qt * 64 + wave * 16;
  const float NEG_INF = -__builtin_inff();
  __shared__ alignas(16) short Ksm[32 * 136];   // [s][d] padded
  __shared__ alignas(16) short Vsm[128 * 40];   // V^T [d][s] padded
  __shared__ alignas(16) short Psm[4][16][40];  // per-wave P [q][s]
  short8 qf[4];
  {
    const short* qrow = qbf + ((size_t)(b * Q_ + q0w + r)) * HID_ + h * D_;
#pragma unroll
    for (int ds = 0; ds < 4; ++ds)
      qf[ds] = *reinterpret_cast<const short8*>(qrow + ds * 32 + G * 8);
  }
  f32x4 acc[8] = {};
  float m_run = NEG_INF, l_run = 0.f;
  const int ntiles = qt * 2 + 2;
  const int my_q = q0w + r;
  const int my_q_hi = q0w + 15;
  const int krow = tid >> 3, kd0 = (tid & 7) * 16;
  const int vd = tid >> 2, vsc = (tid & 3) * 8;
  const short* vt_base = vt + (size_t)(b * 8 + hkv) * 128 * 1024;
  // T14 issue-early registers (one KV tile in flight)
  uint4 kreg0, kreg1, vreg0, vreg1;
  auto preload = [&](int st) {
    const short* gk = kv + ((size_t)(b * Q_ + st * 32 + krow)) * 2048 + hkv * D_ + kd0;
    kreg0 = *reinterpret_cast<const uint4*>(gk);
    kreg1 = *reinterpret_cast<const uint4*>(gk + 8);
    vreg0 = *reinterpret_cast<const uint4*>(vt_base + (size_t)vd * 1024 + st * 32 + vsc);
    vreg1 = *reinterpret_cast<const uint4*>(vt_base + (size_t)(vd + 64) * 1024 + st * 32 + vsc);
  };
  preload(0);
  for (int st = 0; st < ntiles; ++st) {
    __syncthreads();
    {
      *reinterpret_cast<uint4*>(&Ksm[krow * 136 + kd0])     = kreg0;
      *reinterpret_cast<uint4*>(&Ksm[krow * 136 + kd0 + 8]) = kreg1;
      *reinterpret_cast<uint4*>(&Vsm[vd * 40 + vsc])        = vreg0;
      *reinterpret_cast<uint4*>(&Vsm[(vd + 64) * 40 + vsc]) = vreg1;
    }
    __syncthreads();
    if (st + 1 < ntiles) preload(st + 1);   // latency hides under compute below
    if (st * 32 <= my_q_hi) {
      f32x4 sacc[2] = {};
      __builtin_amdgcn_s_setprio(1);
#pragma unroll
      for (int sb = 0; sb < 2; ++sb)
#pragma unroll
        for (int ds = 0; ds < 4; ++ds) {
          short8 kf = *reinterpret_cast<const short8*>(&Ksm[(sb * 16 + r) * 136 + ds * 32 + G * 8]);
          sacc[sb] = mfma16x16x32(kf, qf[ds], sacc[sb]);
        }
      __builtin_amdgcn_s_setprio(0);
      float vals[8];
      float mymax = NEG_INF;
#pragma unroll
      for (int sb = 0; sb < 2; ++sb)
#pragma unroll
        for (int j = 0; j < 4; ++j) {
          int sIdx = st * 32 + sb * 16 + G * 4 + j;
          float v = sacc[sb][j] * SCALE_;
          v = (sIdx <= my_q) ? v : NEG_INF;
          vals[sb * 4 + j] = v;
          mymax = fmaxf(mymax, v);
        }
      mymax = fmaxf(mymax, __shfl_xor(mymax, 16));
      mymax = fmaxf(mymax, __shfl_xor(mymax, 32));
      float m_new = fmaxf(m_run, mymax);
      float factor = __expf(m_run - m_new);
      float psum = 0.f;
      float pv_[8];
#pragma unroll
      for (int i = 0; i < 8; ++i) {
        float p = __expf(vals[i] - m_new);
        psum += p;
        pv_[i] = p;
      }
      psum += __shfl_xor(psum, 16);
      psum += __shfl_xor(psum, 32);
      l_run = l_run * factor + psum;
      m_run = m_new;
#pragma unroll
      for (int i = 0; i < 8; ++i)
        Psm[wave][r][(i >> 2) * 16 + G * 4 + (i & 3)] = f2bf(pv_[i]);
      asm volatile("s_waitcnt lgkmcnt(0)" ::: "memory");
      __builtin_amdgcn_sched_barrier(0);
      short8 pf = *reinterpret_cast<const short8*>(&Psm[wave][r][G * 8]);
      float frow[4];
#pragma unroll
      for (int rr = 0; rr < 4; ++rr) frow[rr] = __shfl(factor, G * 4 + rr);
#pragma unroll
      for (int dt = 0; dt < 8; ++dt)
#pragma unroll
        for (int rr = 0; rr < 4; ++rr) acc[dt][rr] *= frow[rr];
      __builtin_amdgcn_s_setprio(1);
#pragma unroll
      for (int dt = 0; dt < 8; ++dt) {
        short8 vf = *reinterpret_cast<const short8*>(&Vsm[(dt * 16 + r) * 40 + G * 8]);
        acc[dt] = mfma16x16x32(pf, vf, acc[dt]);
      }
      __builtin_amdgcn_s_setprio(0);
    }
  }
  float inv = 1.0f / l_run;
  float irow[4];
#pragma unroll
  for (int rr = 0; rr < 4; ++rr) irow[rr] = __shfl(inv, G * 4 + rr);
#pragma unroll
  for (int dt = 0; dt < 8; ++dt)
#pragma unroll
    for (int rr = 0; rr < 4; ++rr) {
      size_t rowi = (size_t)(b * Q_ + q0w + G * 4 + rr) * HID_;
      attn[rowi + h * D_ + dt * 16 + r] = f2bf(acc[dt][rr] * irow[rr]);
    }
}

// ---------------- launch ----------------
extern "C" void kernel_launch(void* const* d_in, const int* in_sizes, int n_in,
                              void* d_out, int out_size, void* d_ws, size_t ws_size,
                              hipStream_t stream) {
  const float* hidden = (const float*)d_in[0];
  const float* w_qkv  = (const float*)d_in[1];
  const float* w_o    = (const float*)d_in[2];
  float* out = (float*)d_out;
  char* ws = (char*)d_ws;
  char* od = (char*)d_out;
  // scratch layout (ws 64 MiB + d_out 64 MiB):
  //   d_out[ 0:32M) hid_bf   -> dead after GEMM1
  //   d_out[32M:64M) q_bf    -> roped; dead after attn
  //   ws   [ 0:48M) wqkvT    -> dead after GEMM1
  //   ws   [48M:64M) kv_ws   -> k-half roped; dead after attn
  //   ws   [32M:40M) v_t     -> written after GEMM1 (dead wqkvT tail); dead after attn
  //   ws   [ 0:32M) attn_bf  (after GEMM1)
  //   ws   [32M:64M) woT     (after attn; clobbers v_t + kv_ws)
  short* hid_bf  = (short*)(od + 0);
  short* q_bf    = (short*)(od + 33554432);
  short* wqkvT   = (short*)(ws + 0);
  short* kv_ws   = (short*)(ws + 50331648);
  short* v_t     = (short*)(ws + 33554432);
  short* attn_bf = (short*)(ws + 0);
  short* woT     = (short*)(ws + 33554432);

  k_cvt<<<dim3(16384), dim3(256), 0, stream>>>(hidden, hid_bf, HID_ * B_ * Q_);
  k_cvt_t<<<dim3(192, 128), dim3(256), 0, stream>>>(w_qkv, wqkvT, HID_, NQKV_);
  // GEMM1: one dispatch, N=6144 (48x32 = 1536 wgs), BK=64 double-stage
  k_gemm1<<<dim3(48, 32), dim3(256), 0, stream>>>(hid_bf, wqkvT, q_bf, kv_ws);
  // fused prep: rope (q + k-half) overlapped with V transpose -> v_t
  k_prep<<<dim3(B_ * Q_ + 4096), dim3(256), 0, stream>>>(q_bf, kv_ws, v_t);
  // attention -> attn_bf (ws+0, wqkvT dead)
  k_attn<<<dim3(16, 32, 4), dim3(256), 0, stream>>>(q_bf, kv_ws, v_t, attn_bf);
  // w_o^T into ws[32M:64M) (v_t + kv dead after attn), then GEMM2 -> d_out f32
  k_cvt_t<<<dim3(128, 128), dim3(256), 0, stream>>>(w_o, woT, HID_, HID_);
  // GEMM2: 128x128 tiles
  k_gemm2<<<dim3(32, 32), dim3(256), 0, stream>>>(attn_bf, woT, out);
}